// Round 13
// baseline (1241.524 us; speedup 1.0000x reference)
//
#include <hip/hip_runtime.h>
#include <hip/hip_bf16.h>
#include <hip/hip_fp16.h>
#include <stdint.h>

// Problem constants (QLoRALinear_34454227649197)
#define M_DIM 16384   // TOK
#define N_DIM 4096    // OUT
#define K_DIM 4096    // IN
#define NGROUP 64     // K_DIM / 64
#define NT    64      // K-tiles (K_DIM / 64), even

// Harness dtype note (round-3 forensics): float16 arrays are presented as
// FLOAT32 on device. x = const float*, out = float*.

typedef _Float16 f16x8 __attribute__((ext_vector_type(8)));
typedef _Float16 f16x2 __attribute__((ext_vector_type(2)));
typedef float f32x4 __attribute__((ext_vector_type(4)));

typedef __attribute__((address_space(3))) uint32_t lds_u32_t;
typedef const __attribute__((address_space(1))) uint32_t glob_u32_t;

__device__ __forceinline__ void gload16(const void* g, void* l) {
    // global_load_lds_dwordx4: LDS dest = wave-uniform base + lane*16;
    // global source per-lane (pre-swizzled). Zero conflicts rounds 5-12.
    __builtin_amdgcn_global_load_lds((glob_u32_t*)g, (lds_u32_t*)l, 16, 0, 0);
}

// ---------------------------------------------------------------------------
// Kernel 0: Xh[i] = (fp16) x[i]   (exact: x values are fp16-quantized)
// ---------------------------------------------------------------------------
__global__ __launch_bounds__(256) void convert_x_kernel(
    const float* __restrict__ x, _Float16* __restrict__ Xh)
{
    const size_t i = ((size_t)blockIdx.x * 256 + threadIdx.x) * 8;
    const float4 a = *reinterpret_cast<const float4*>(&x[i]);
    const float4 b = *reinterpret_cast<const float4*>(&x[i + 4]);
    f16x8 o;
    o[0] = (_Float16)a.x; o[1] = (_Float16)a.y;
    o[2] = (_Float16)a.z; o[3] = (_Float16)a.w;
    o[4] = (_Float16)b.x; o[5] = (_Float16)b.y;
    o[6] = (_Float16)b.z; o[7] = (_Float16)b.w;
    *reinterpret_cast<f16x8*>(&Xh[i]) = o;
}

// ---------------------------------------------------------------------------
// Kernel 1: W[local n][k] = (q[n0+n][k]-8)*scales[n0+n][k/64]
//                           + sum_r lB[n0+n][r]*lA[r][k]     (fp16 out)
// ---------------------------------------------------------------------------
__global__ __launch_bounds__(256) void dequant_lora_kernel(
    const int* __restrict__ q, const float* __restrict__ sc,
    const float* __restrict__ lA, const float* __restrict__ lB,
    _Float16* __restrict__ W, int n0)
{
    const int t   = threadIdx.x;
    const int o0l = blockIdx.x * 4;        // local chunk row base
    const int o0g = n0 + o0l;              // global OUT row base

    __shared__ float sScale[4][64];
    __shared__ float sB[4][16];
    sScale[t >> 6][t & 63] = sc[(size_t)(o0g + (t >> 6)) * NGROUP + (t & 63)];
    if (t < 64) sB[t >> 4][t & 15] = lB[(size_t)(o0g + (t >> 4)) * 16 + (t & 15)];
    __syncthreads();

    for (int j = 0; j < 8; ++j) {
        const int i = j * 512 + t * 2;      // even; covers [0,4096)
        float l0[4] = {0.f, 0.f, 0.f, 0.f};
        float l1[4] = {0.f, 0.f, 0.f, 0.f};
        #pragma unroll
        for (int r = 0; r < 16; ++r) {
            const float2 a = *reinterpret_cast<const float2*>(&lA[(size_t)r * K_DIM + i]);
            #pragma unroll
            for (int row = 0; row < 4; ++row) {
                l0[row] = fmaf(sB[row][r], a.x, l0[row]);
                l1[row] = fmaf(sB[row][r], a.y, l1[row]);
            }
        }
        const int g = i >> 6;               // i even => i, i+1 same group
        #pragma unroll
        for (int row = 0; row < 4; ++row) {
            const int2 qv = *reinterpret_cast<const int2*>(&q[(size_t)(o0g + row) * K_DIM + i]);
            const float s = sScale[row][g];
            f16x2 h2;
            h2[0] = (_Float16)fmaf((float)(qv.x - 8), s, l0[row]);
            h2[1] = (_Float16)fmaf((float)(qv.y - 8), s, l1[row]);
            *reinterpret_cast<f16x2*>(&W[(size_t)(o0l + row) * K_DIM + i]) = h2;
        }
    }
}

// ---------------------------------------------------------------------------
// Kernel 2: out = Xh @ W^T — 128x128 tile, BK=64, 256 thr = 4 waves (2M x 2N,
// each wave 64x64 = 4x4 frags, acc=64 regs). B-operand in REGISTERS
// (global->reg, L2-served, even/odd sets prefetched 1 tile ahead); A
// LDS-staged via DMA (32 KB dbuf).
// REGISTER BUDGET (R11/R12 lesson): 512-thr blocks force >=2 waves/EU ->
// 256-reg total cap; acc 128 left no room -> permanent spill (VGPR=128 at
// cap, 846us). At 256 thr + acc 64: total ~200 <= 256 -> fits at
// __launch_bounds__(256,2) -> TWO independent blocks/CU -> cross-block
// async overlap (m114; R5's 56% MfmaUtil mechanism) hides staging drains.
// Per-CU pipes/tile-pair: MFMA 1242cy > LDS ~1030cy > L2-B ~1170cy,
// on three different resources.
// ---------------------------------------------------------------------------
#define ABUF_BYTES 16384              // A buffer: 128 rows x 128 B

__global__ __launch_bounds__(256, 2) void gemm_bt_kernel(
    const _Float16* __restrict__ A,   // Xh chunk, [rows][K]
    const _Float16* __restrict__ B,   // W chunk,  [cols][K]
    float* __restrict__ C,
    int m0, int n0, int nbm, int nbn)
{
    alignas(16) __shared__ _Float16 lds[2 * 8192];   // 32 KiB (A only)

    const int t  = threadIdx.x;
    const int l  = t & 63;
    const int w  = t >> 6;          // 0..3
    const int wr = w >> 1;          // 0..1  (M: 64 rows)
    const int wc = w & 1;           // 0..1  (N: 64 cols)

    // m204 bijective XCD swizzle, then tail-safe GROUP_M=8.
    const int nwg  = nbm * nbn;
    const int orig = blockIdx.x;
    const int xcd  = orig & 7;
    const int qq = nwg >> 3, rr = nwg & 7;
    const int wg = (xcd < rr ? xcd * (qq + 1) : rr * (qq + 1) + (xcd - rr) * qq)
                 + (orig >> 3);
    const int gs    = 8 * nbn;
    const int group = wg / gs;
    const int start = group * 8;
    const int gsz   = (nbm - start < 8) ? (nbm - start) : 8;
    const int idg   = wg - group * gs;
    const int bm    = start + idg % gsz;
    const int bn    = idg / gsz;

    const int Mb = bm * 128;
    const int Nb = bn * 128;

    // A staging: 256 thr x 16B = 4 KB = 32 rows x 128 B per issue; 4 issues
    // per K-tile. Thread t -> row rloc = t>>3 (+n*32), phys slot t&7; source
    // k-off = ((t&7)^(rloc&7))*8 (inverse swizzle on global side).
    const int rloc = t >> 3;                   // 0..31
    const int kswz = ((t & 7) ^ (rloc & 7)) * 8;
    const _Float16* aSrc = A + (size_t)(Mb + rloc) * K_DIM + kswz;
    char* const ldsBase = (char*)lds;
    const int dOff = t * 16;

    const int r16 = l & 15;
    const int hi  = l >> 4;           // 0..3
    const int swzB = (r16 & 7) * 16;  // row-dependent XOR part (bytes)

    // B fragment bases (hoisted): lane reads B[Nb+wc*64+i*16+r16][k..k+8).
    const _Float16* bBase0 = B + (size_t)(Nb + wc * 64 + r16) * K_DIM + hi * 8;
    const _Float16* bBase1 = bBase0 + 32;   // ks=1 k-offset

    f32x4 acc[4][4] = {};
    f16x8 bE[8], bO[8];   // even/odd tile B reg sets: [ks*4 + ni]

    // STAGE_A(kt1): DMA A tile kt1 into buf[kt1&1].
    auto STAGE_A = [&](int kt1) {
        char* d = ldsBase + (kt1 & 1) * ABUF_BYTES + dOff;
        const int kp = kt1 * 64;
        #pragma unroll
        for (int n = 0; n < 4; ++n)
            gload16(aSrc + (size_t)(n * 32) * K_DIM + kp, d + n * 4096);
    };

    // LOADB(dst, kt2): 8 reg loads covering this wave's B-quarter, K-tile kt2.
    #define LOADB(dst, kt2) do {                                            \
        _Pragma("unroll")                                                   \
        for (int i_ = 0; i_ < 4; ++i_) {                                    \
            dst[i_]     = *(const f16x8*)(bBase0                            \
                + (size_t)(i_ * 16) * K_DIM + (kt2) * 64);                  \
            dst[4 + i_] = *(const f16x8*)(bBase1                            \
                + (size_t)(i_ * 16) * K_DIM + (kt2) * 64);                  \
        }                                                                   \
    } while (0)

    // COMPUTE(bufIdx, bSet): one K-tile of MFMA from LDS-A + reg-B.
    #define COMPUTE(bufIdx, bSet) do {                                      \
        const char* Ac = ldsBase + (bufIdx) * ABUF_BYTES;                   \
        _Pragma("unroll")                                                   \
        for (int ks = 0; ks < 2; ++ks) {                                    \
            f16x8 aF[4];                                                    \
            const int swz = ((ks * 4 + hi) * 16) ^ swzB;                    \
            _Pragma("unroll")                                               \
            for (int i = 0; i < 4; ++i)                                     \
                aF[i] = *(const f16x8*)(Ac +                                \
                    (wr * 64 + i * 16 + r16) * 128 + swz);                  \
            __builtin_amdgcn_s_setprio(1);                                  \
            _Pragma("unroll")                                               \
            for (int mi = 0; mi < 4; ++mi)                                  \
                _Pragma("unroll")                                           \
                for (int ni = 0; ni < 4; ++ni)                              \
                    acc[mi][ni] =                                           \
                        __builtin_amdgcn_mfma_f32_16x16x32_f16(             \
                            aF[mi], bSet[ks * 4 + ni],                      \
                            acc[mi][ni], 0, 0, 0);                          \
            __builtin_amdgcn_s_setprio(0);                                  \
        }                                                                   \
    } while (0)

    // Prologue: stage A(0), preload B(0) into even set.
    STAGE_A(0);
    LOADB(bE, 0);

    for (int kt = 0; kt < NT; kt += 2) {
        // EVEN tile kt: consume bE; prefetch kt+1 (A DMA + B regs).
        __syncthreads();              // publishes A[kt]; outstanding loads
                                      // issued >= 1 tile ago; residual stall
                                      // covered by the co-resident block.
        STAGE_A(kt + 1);              // kt+1 <= 63 always (NT even)
        LOADB(bO, kt + 1);
        COMPUTE(kt & 1, bE);

        // ODD tile kt+1: consume bO; prefetch kt+2.
        __syncthreads();
        if (kt + 2 < NT) {
            STAGE_A(kt + 2);
            LOADB(bE, kt + 2);
        }
        COMPUTE((kt + 1) & 1, bO);
    }

    // Epilogue: C/D layout col = lane&15, row = (lane>>4)*4 + reg. f32 stores.
    #pragma unroll
    for (int mi = 0; mi < 4; ++mi) {
        const int row0 = m0 + Mb + wr * 64 + mi * 16 + hi * 4;
        #pragma unroll
        for (int ni = 0; ni < 4; ++ni) {
            const int col = n0 + Nb + wc * 64 + ni * 16 + r16;
            const f32x4 v = acc[mi][ni];
            #pragma unroll
            for (int u = 0; u < 4; ++u)
                C[(size_t)(row0 + u) * N_DIM + col] = v[u];
        }
    }
    #undef LOADB
    #undef COMPUTE
}

extern "C" void kernel_launch(void* const* d_in, const int* in_sizes, int n_in,
                              void* d_out, int out_size, void* d_ws, size_t ws_size,
                              hipStream_t stream) {
    const float* x  = (const float*)d_in[0];   // fp16 values promoted to f32
    const int*   q  = (const int*)d_in[1];
    const float* sc = (const float*)d_in[2];
    const float* lA = (const float*)d_in[3];
    const float* lB = (const float*)d_in[4];
    float* out = (float*)d_out;                 // f32 output buffer

    // Workspace layout: [W: colC x K fp16][Xh: rowC x K fp16], chunk-looped.
    const size_t wfull = (size_t)N_DIM * K_DIM * 2;   // 32 MiB
    int colC, rowC;
    if (ws_size >= wfull + (size_t)128 * K_DIM * 2) {
        colC = N_DIM;
        size_t rows = (ws_size - wfull) / ((size_t)K_DIM * 2);
        rowC = (int)((rows / 128) * 128);
        if (rowC > M_DIM) rowC = M_DIM;
    } else {
        size_t half = ws_size / 2;
        colC = (int)((half / ((size_t)K_DIM * 2) / 128) * 128);
        if (colC < 128) colC = 128;
        if (colC > N_DIM) colC = N_DIM;
        size_t rows = (ws_size - (size_t)colC * K_DIM * 2) / ((size_t)K_DIM * 2);
        rowC = (int)((rows / 128) * 128);
        if (rowC < 128) rowC = 128;
        if (rowC > M_DIM) rowC = M_DIM;
    }
    _Float16* W  = (_Float16*)d_ws;
    _Float16* Xh = (_Float16*)d_ws + (size_t)colC * K_DIM;

    for (int n0 = 0; n0 < N_DIM; n0 += colC) {
        int cols = N_DIM - n0; if (cols > colC) cols = colC;
        dequant_lora_kernel<<<cols / 4, 256, 0, stream>>>(q, sc, lA, lB, W, n0);
        for (int m0 = 0; m0 < M_DIM; m0 += rowC) {
            int rows = M_DIM - m0; if (rows > rowC) rows = rowC;
            convert_x_kernel<<<(int)(((size_t)rows * K_DIM) / (256 * 8)), 256, 0, stream>>>(
                x + (size_t)m0 * K_DIM, Xh);
            gemm_bt_kernel<<<(rows / 128) * (cols / 128), 256, 0, stream>>>(
                Xh, W, out, m0, n0, rows / 128, cols / 128);
        }
    }
}

// Round 14
// 599.505 us; speedup vs baseline: 2.0709x; 2.0709x over previous
//
#include <hip/hip_runtime.h>
#include <hip/hip_bf16.h>
#include <hip/hip_fp16.h>
#include <stdint.h>

// Problem constants (QLoRALinear_34454227649197)
#define M_DIM 16384   // TOK
#define N_DIM 4096    // OUT
#define K_DIM 4096    // IN
#define NGROUP 64     // K_DIM / 64
#define NT    64      // K-tiles (K_DIM / 64), even

// Harness dtype note (round-3 forensics): float16 arrays are presented as
// FLOAT32 on device. x = const float*, out = float*.

typedef _Float16 f16x8 __attribute__((ext_vector_type(8)));
typedef _Float16 f16x2 __attribute__((ext_vector_type(2)));
typedef float f32x4 __attribute__((ext_vector_type(4)));

typedef __attribute__((address_space(3))) uint32_t lds_u32_t;
typedef const __attribute__((address_space(1))) uint32_t glob_u32_t;

__device__ __forceinline__ void gload16(const void* g, void* l) {
    // global_load_lds_dwordx4: LDS dest = wave-uniform base + lane*16;
    // global source per-lane (pre-swizzled). Zero conflicts rounds 5-12.
    __builtin_amdgcn_global_load_lds((glob_u32_t*)g, (lds_u32_t*)l, 16, 0, 0);
}

// ---------------------------------------------------------------------------
// Kernel 0: Xh[i] = (fp16) x[i]   (exact: x values are fp16-quantized)
// ---------------------------------------------------------------------------
__global__ __launch_bounds__(256) void convert_x_kernel(
    const float* __restrict__ x, _Float16* __restrict__ Xh)
{
    const size_t i = ((size_t)blockIdx.x * 256 + threadIdx.x) * 8;
    const float4 a = *reinterpret_cast<const float4*>(&x[i]);
    const float4 b = *reinterpret_cast<const float4*>(&x[i + 4]);
    f16x8 o;
    o[0] = (_Float16)a.x; o[1] = (_Float16)a.y;
    o[2] = (_Float16)a.z; o[3] = (_Float16)a.w;
    o[4] = (_Float16)b.x; o[5] = (_Float16)b.y;
    o[6] = (_Float16)b.z; o[7] = (_Float16)b.w;
    *reinterpret_cast<f16x8*>(&Xh[i]) = o;
}

// ---------------------------------------------------------------------------
// Kernel 1: W[local n][k] = (q[n0+n][k]-8)*scales[n0+n][k/64]
//                           + sum_r lB[n0+n][r]*lA[r][k]     (fp16 out)
// ---------------------------------------------------------------------------
__global__ __launch_bounds__(256) void dequant_lora_kernel(
    const int* __restrict__ q, const float* __restrict__ sc,
    const float* __restrict__ lA, const float* __restrict__ lB,
    _Float16* __restrict__ W, int n0)
{
    const int t   = threadIdx.x;
    const int o0l = blockIdx.x * 4;        // local chunk row base
    const int o0g = n0 + o0l;              // global OUT row base

    __shared__ float sScale[4][64];
    __shared__ float sB[4][16];
    sScale[t >> 6][t & 63] = sc[(size_t)(o0g + (t >> 6)) * NGROUP + (t & 63)];
    if (t < 64) sB[t >> 4][t & 15] = lB[(size_t)(o0g + (t >> 4)) * 16 + (t & 15)];
    __syncthreads();

    for (int j = 0; j < 8; ++j) {
        const int i = j * 512 + t * 2;      // even; covers [0,4096)
        float l0[4] = {0.f, 0.f, 0.f, 0.f};
        float l1[4] = {0.f, 0.f, 0.f, 0.f};
        #pragma unroll
        for (int r = 0; r < 16; ++r) {
            const float2 a = *reinterpret_cast<const float2*>(&lA[(size_t)r * K_DIM + i]);
            #pragma unroll
            for (int row = 0; row < 4; ++row) {
                l0[row] = fmaf(sB[row][r], a.x, l0[row]);
                l1[row] = fmaf(sB[row][r], a.y, l1[row]);
            }
        }
        const int g = i >> 6;               // i even => i, i+1 same group
        #pragma unroll
        for (int row = 0; row < 4; ++row) {
            const int2 qv = *reinterpret_cast<const int2*>(&q[(size_t)(o0g + row) * K_DIM + i]);
            const float s = sScale[row][g];
            f16x2 h2;
            h2[0] = (_Float16)fmaf((float)(qv.x - 8), s, l0[row]);
            h2[1] = (_Float16)fmaf((float)(qv.y - 8), s, l1[row]);
            *reinterpret_cast<f16x2*>(&W[(size_t)(o0l + row) * K_DIM + i]) = h2;
        }
    }
}

// ---------------------------------------------------------------------------
// Kernel 2: out = Xh @ W^T — 256x256, BK=64, 8 waves (2M x 4N, 128x64/wave).
// R10 schedule with m201-faithful EVEN read distribution (R14 change):
// reads spread 8/4/8/4 across the 4 phases (was 8/12/4/0); each phase's
// 16-MFMA cluster consumes reads issued in the SAME phase before its
// barrier (bF0 held across P1-P2, bF1 across P3-P4). Staging, vmcnt(4)
// ledger, raw-barrier structure identical to R10:
//   P1 stage kt+1 Bh0 | P2 stage kt+1 Bh1 (A of buf[kt] dead after P2? no -
//   A reads now extend to P4, but A restage targets buf[kt] only via kt+2
//   staged in P3/P4 *after* the relevant quadrant reads: see in-line notes).
// Liveness re-check for R14 read order:
//   - P3 stages kt+2 Ah0 into buf[kt&1] A-region rows 0-127. P3/P4 still
//     READ A rows (aF2: mq0 rows wr*128+0..63; aF3: mq1 rows wr*128+64..127)
//     of buf[kt&1]! RACE? No: P3's stage is issued AFTER P3's reads in
//     program order per wave, but other waves' DMA could land early. FIX:
//     read aF2 AND aF3 in P3 (8 reads), P4 reads nothing from A. Spread
//     becomes 8/4/12/0... that's R10 again. Instead: keep A-read front-load
//     in P1-P2 (aF0,aF1,aF2,aF3 = 16 reads? no...). Resolution: swap roles -
//     front-load all A reads P1/P2 (safe for P3/P4 restage) but bind MFMA
//     so each cluster consumes same-phase reads:
//       P1: rd bF0(4) + aF0(4)           -> MFMA(aF0,bF0)
//       P2: rd aF1(4) + aF2(4) + aF3(4)  -> MFMA(aF1,bF0)   [12 reads]
//       P3: rd bF1(4); stage kt+2 Ah0    -> MFMA(aF2,bF1)
//       P4: stage kt+2 Ah1; vmcnt(4)     -> MFMA(aF3,bF1)
//     = R10's distribution. The A-region WAR constraint FORCES 8/12/4/0.
//     Therefore R14's even spread applies to the B-side instead: move bF1's
//     read to P2 (B-region of buf[kt] is never restaged this tile - only
//     kt+1's B goes to the OTHER buffer): P1: bF0+aF0 (8); P2: aF1+bF1 (8);
//     P3: aF2 (4) + stage Ah0; P4: aF3 (4) + stage Ah1 + vmcnt. A-reads in
//     P3/P4 RACE with Ah0/Ah1 restage... aF2 reads rows of mq0, Ah0 stages
//     rows 0-127 = same region. RACE again. Final resolution: restage
//     kt+2's A into the B-ORDER: stage kt+2 Bh0/Bh1 in P1/P2 (B of buf[kt]
//     read only as bF0/bF1 in P1/P2 - bind stage AFTER reads in same phase,
//     cross-wave safe because B-half h of buf[kt&1] is only restaged at
//     tile kt+2 ... NO - kt+1's B targets buf[(kt+1)&1] (other buffer), so
//     B restage into buf[kt&1] happens for tile kt+2 during THIS tile's
//     P1/P2. bF0 is read in P1 from buf[kt&1]; kt+2's Bh0 stage into the
//     SAME region in P1 races other waves' reads. Same problem.
//   CONCLUSION: with 2 buffers + 1.5-tile lookahead, SOME region must be
//   restaged while the tile still reads it; the only safe dead region is
//   one whose reads are complete before the staging phase -> front-loaded
//   A (R10) is the unique consistent choice. R14 therefore keeps R10's
//   read sets but splits P2's 12-read burst by moving MFMA binding:
//       P1: rd bF0(4), aF0(4); stage Bh0(kt+1) -> MFMA(aF0,bF0)
//       P2: rd aF1(4), aF2(4); stage Bh1(kt+1) -> MFMA(aF1,bF0)
//       P3: rd aF3(4), bF1(4); stage Ah0(kt+2) -> MFMA(aF2,bF1)
//           [A-region restage vs aF3 read: aF3 read is issued BEFORE the
//            stage in P3 per-wave, but cross-wave DMA hazard remains ->
//            put one extra s_barrier between the reads and the stage in P3]
//       P4: stage Ah1(kt+2); vmcnt(4) -> MFMA(aF3,bF1)
//   Reads: 8/8/8/0 (vs 8/12/4/0), one extra barrier in P3 (9/tile).
// ---------------------------------------------------------------------------
#define ABUF 32768                    // A region: 256 rows x 128 B
#define BUF_BYTES 65536               // A (32K) + B (32K)
#define NT4 (NT * 4)

#define RD_A(dst, mq, ks) do {                                              \
    const int swz_ = ((((ks) * 4 + hi) * 16) ^ swzB);                       \
    _Pragma("unroll")                                                       \
    for (int i_ = 0; i_ < 4; ++i_)                                          \
        dst[i_] = *(const f16x8*)(Ac +                                      \
            (wr * 128 + (mq) * 64 + i_ * 16 + r16) * 128 + swz_);           \
} while (0)

#define RD_B(dst, ks) do {                                                  \
    const int swz_ = ((((ks) * 4 + hi) * 16) ^ swzB);                       \
    _Pragma("unroll")                                                       \
    for (int i_ = 0; i_ < 4; ++i_)                                          \
        dst[i_] = *(const f16x8*)(Bc +                                      \
            (wc * 64 + i_ * 16 + r16) * 128 + swz_);                        \
} while (0)

#define MFMA16(aF, bF, mq) do {                                             \
    __builtin_amdgcn_s_setprio(1);                                          \
    _Pragma("unroll")                                                       \
    for (int mi_ = 0; mi_ < 4; ++mi_)                                       \
        _Pragma("unroll")                                                   \
        for (int ni_ = 0; ni_ < 4; ++ni_)                                   \
            acc[(mq) * 4 + mi_][ni_] = __builtin_amdgcn_mfma_f32_16x16x32_f16( \
                aF[mi_], bF[ni_], acc[(mq) * 4 + mi_][ni_], 0, 0, 0);       \
    __builtin_amdgcn_s_setprio(0);                                          \
} while (0)

__global__ __launch_bounds__(512, 1) void gemm_bt_kernel(
    const _Float16* __restrict__ A,   // Xh chunk, [rows][K]
    const _Float16* __restrict__ B,   // W chunk,  [cols][K]
    float* __restrict__ C,
    int m0, int n0, int nbm, int nbn)
{
    alignas(16) __shared__ _Float16 lds[2 * 32768];   // 128 KiB

    const int t  = threadIdx.x;
    const int l  = t & 63;
    const int w  = t >> 6;          // 0..7
    const int wr = w >> 2;          // 0..1  (M: 128 rows)
    const int wc = w & 3;           // 0..3  (N: 64 cols)

    // m204 bijective XCD swizzle, then tail-safe GROUP_M=8.
    const int nwg  = nbm * nbn;
    const int orig = blockIdx.x;
    const int xcd  = orig & 7;
    const int qq = nwg >> 3, rr = nwg & 7;
    const int wg = (xcd < rr ? xcd * (qq + 1) : rr * (qq + 1) + (xcd - rr) * qq)
                 + (orig >> 3);
    const int gs    = 8 * nbn;
    const int group = wg / gs;
    const int start = group * 8;
    const int gsz   = (nbm - start < 8) ? (nbm - start) : 8;
    const int idg   = wg - group * gs;
    const int bm    = start + idg % gsz;
    const int bn    = idg / gsz;

    const int Mb = bm * 256;
    const int Nb = bn * 256;

    // Shared staging: 512 thr x 16B = 8 KB = 64 rows x 128 B per issue.
    const int rloc = t >> 3;                   // 0..63
    const int kswz = ((t & 7) ^ (rloc & 7)) * 8;
    const _Float16* aSrc = A + (size_t)(Mb + rloc) * K_DIM + kswz;
    const _Float16* bSrc = B + (size_t)(Nb + rloc) * K_DIM + kswz;
    char* const ldsBase = (char*)lds;
    const int dOff = t * 16;

    const int r16 = l & 15;
    const int hi  = l >> 4;           // 0..3
    const int swzB = (r16 & 7) * 16;  // row-dependent XOR part (bytes)

    // STAGEH(j): stage half-tile j (= kt*4 + h; h: 0=Ah0,1=Ah1,2=Bh0,3=Bh1)
    // into buf[(j>>2)&1]. 2 gload16/thread (128 rows).
    auto STAGEH = [&](int j) {
        if (j >= NT4) return;
        const int ktj = j >> 2, h = j & 3;
        const _Float16* src = ((h >> 1) ? bSrc : aSrc)
                            + (size_t)((h & 1) * 128) * K_DIM + ktj * 64;
        char* d = ldsBase + (ktj & 1) * BUF_BYTES
                + ((h >> 1) ? ABUF : 0) + (h & 1) * 16384 + dOff;
        gload16(src, d);
        gload16(src + (size_t)64 * K_DIM, d + 8192);
    };

    f32x4 acc[8][4] = {};
    f16x8 aF0[4], aF1[4], aF2[4], aF3[4], bF0[4], bF1[4];

    // Prologue: kt0 h0-h3 + kt1 A halves; counted wait; publish.
    STAGEH(0); STAGEH(1); STAGEH(2); STAGEH(3); STAGEH(4); STAGEH(5);
    asm volatile("s_waitcnt vmcnt(4)" ::: "memory");   // kt0 landed
    __builtin_amdgcn_s_barrier();

    for (int kt = 0; kt < NT; ++kt) {
        const char* Ac = ldsBase + (kt & 1) * BUF_BYTES;
        const char* Bc = Ac + ABUF;
        const int j1 = 4 * (kt + 1), j2 = 4 * (kt + 2);

        // P1: read bF0 + aF0 (8 ds_read); stage kt+1 Bh0.
        RD_B(bF0, 0);
        RD_A(aF0, 0, 0);
        STAGEH(j1 + 2);
        __builtin_amdgcn_s_barrier();
        MFMA16(aF0, bF0, 0);
        __builtin_amdgcn_s_barrier();

        // P2: read aF1 + aF2 (8 ds_read); stage kt+1 Bh1.
        RD_A(aF1, 1, 0);
        RD_A(aF2, 0, 1);
        STAGEH(j1 + 3);
        __builtin_amdgcn_s_barrier();
        MFMA16(aF1, bF0, 1);
        __builtin_amdgcn_s_barrier();

        // P3: read aF3 + bF1 (8 ds_read); THEN barrier; THEN restage kt+2
        // Ah0 into buf[kt&1] (all waves' A reads complete at the barrier).
        RD_A(aF3, 1, 1);
        RD_B(bF1, 1);
        __builtin_amdgcn_s_barrier();        // A reads of all waves retired
        __builtin_amdgcn_sched_barrier(0);   // keep stage below the barrier
        STAGEH(j2 + 0);
        MFMA16(aF2, bF1, 0);
        __builtin_amdgcn_s_barrier();

        // P4: stage kt+2 Ah1; counted gate; pure-register MFMA.
        STAGEH(j2 + 1);
        if (kt + 2 < NT) {
            asm volatile("s_waitcnt vmcnt(4)" ::: "memory");  // kt+1 resident
        } else if (kt + 1 < NT) {
            asm volatile("s_waitcnt vmcnt(0)" ::: "memory");  // final fill
        }
        __builtin_amdgcn_s_barrier();
        MFMA16(aF3, bF1, 1);
        __builtin_amdgcn_s_barrier();
    }

    // Epilogue: C/D layout col = lane&15, row = (lane>>4)*4 + reg. f32 stores.
    #pragma unroll
    for (int mi = 0; mi < 8; ++mi) {
        const int row0 = m0 + Mb + wr * 128 + mi * 16 + hi * 4;
        #pragma unroll
        for (int ni = 0; ni < 4; ++ni) {
            const int col = n0 + Nb + wc * 64 + ni * 16 + r16;
            const f32x4 v = acc[mi][ni];
            #pragma unroll
            for (int u = 0; u < 4; ++u)
                C[(size_t)(row0 + u) * N_DIM + col] = v[u];
        }
    }
}

extern "C" void kernel_launch(void* const* d_in, const int* in_sizes, int n_in,
                              void* d_out, int out_size, void* d_ws, size_t ws_size,
                              hipStream_t stream) {
    const float* x  = (const float*)d_in[0];   // fp16 values promoted to f32
    const int*   q  = (const int*)d_in[1];
    const float* sc = (const float*)d_in[2];
    const float* lA = (const float*)d_in[3];
    const float* lB = (const float*)d_in[4];
    float* out = (float*)d_out;                 // f32 output buffer

    // Workspace layout: [W: colC x K fp16][Xh: rowC x K fp16], chunk-looped.
    const size_t wfull = (size_t)N_DIM * K_DIM * 2;   // 32 MiB
    int colC, rowC;
    if (ws_size >= wfull + (size_t)256 * K_DIM * 2) {
        colC = N_DIM;
        size_t rows = (ws_size - wfull) / ((size_t)K_DIM * 2);
        rowC = (int)((rows / 256) * 256);
        if (rowC > M_DIM) rowC = M_DIM;
    } else {
        size_t half = ws_size / 2;
        colC = (int)((half / ((size_t)K_DIM * 2) / 256) * 256);
        if (colC < 256) colC = 256;
        if (colC > N_DIM) colC = N_DIM;
        size_t rows = (ws_size - (size_t)colC * K_DIM * 2) / ((size_t)K_DIM * 2);
        rowC = (int)((rows / 256) * 256);
        if (rowC < 256) rowC = 256;
        if (rowC > M_DIM) rowC = M_DIM;
    }
    _Float16* W  = (_Float16*)d_ws;
    _Float16* Xh = (_Float16*)d_ws + (size_t)colC * K_DIM;

    for (int n0 = 0; n0 < N_DIM; n0 += colC) {
        int cols = N_DIM - n0; if (cols > colC) cols = colC;
        dequant_lora_kernel<<<cols / 4, 256, 0, stream>>>(q, sc, lA, lB, W, n0);
        for (int m0 = 0; m0 < M_DIM; m0 += rowC) {
            int rows = M_DIM - m0; if (rows > rowC) rows = rowC;
            convert_x_kernel<<<(int)(((size_t)rows * K_DIM) / (256 * 8)), 256, 0, stream>>>(
                x + (size_t)m0 * K_DIM, Xh);
            gemm_bt_kernel<<<(rows / 256) * (cols / 256), 512, 0, stream>>>(
                Xh, W, out, m0, n0, rows / 256, cols / 256);
        }
    }
}